// Round 2
// baseline (228.179 us; speedup 1.0000x reference)
//
#include <hip/hip_runtime.h>

typedef __attribute__((ext_vector_type(8))) short short8;
typedef __attribute__((ext_vector_type(4))) float floatx4;

__device__ __forceinline__ unsigned short f2bf(float f) {
    unsigned int u = __float_as_uint(f);
    u += 0x7FFFu + ((u >> 16) & 1u);   // round-to-nearest-even
    return (unsigned short)(u >> 16);
}

// W (256x256 f32, [k][n]) -> Wt bf16 [n][k]; also zeros num (replaces memset dispatch)
__global__ __launch_bounds__(256) void k_wt(const float* __restrict__ W,
                                            unsigned short* __restrict__ Wt,
                                            float* __restrict__ num) {
    __shared__ unsigned short tile[64][65];
    const int kt = blockIdx.x >> 2, nt = blockIdx.x & 3;
    const int t = threadIdx.x, c = t & 63, rb = t >> 6;
    // zero num: 16 blocks * 256 threads * float4 = 16384 floats
    ((float4*)num)[(blockIdx.x << 8) + t] = float4{0.f, 0.f, 0.f, 0.f};
#pragma unroll
    for (int i = 0; i < 16; ++i) {
        int r = i * 4 + rb;
        tile[c][r] = f2bf(W[(kt * 64 + r) * 256 + nt * 64 + c]);
    }
    __syncthreads();
#pragma unroll
    for (int i = 0; i < 16; ++i) {
        int n = nt * 64 + i * 4 + rb;
        Wt[n * 256 + kt * 64 + c] = tile[i * 4 + rb][c];
    }
}

// Per block: M=32 rows of x, full K=256, full N=256.
// Waves: (mi = w&1) owns rows mi*16..+15 ; (nj = w>>1) owns n-tiles of parity nj.
// LDS = single 32KB Wt chunk (64 n-rows), XOR-swizzled. 4 blocks/CU target.
__global__ __launch_bounds__(256, 4) void k_main(
        const float* __restrict__ x, const unsigned short* __restrict__ Wt,
        const float* __restrict__ bias, const float* __restrict__ u,
        float* __restrict__ ea_all, float* __restrict__ num) {
    __shared__ __align__(16) unsigned char lds[32768];
    const int tid = threadIdx.x;
    const int lane = tid & 63;
    const int wv = tid >> 6;
    const int mi = wv & 1, nj = wv >> 1;
    const int m0 = blockIdx.x << 5;        // 32 rows/block, 4096 blocks
    const int batch = blockIdx.x >> 6;     // 64 blocks per batch

    // ---- A fragments straight from global x (fp32 -> bf16 in regs) ----
    short8 afrag[8];
    {
        const int r = m0 + (mi << 4) + (lane & 15);
        const float* xr = x + (size_t)r * 256 + ((lane >> 4) << 3);
#pragma unroll
        for (int ks = 0; ks < 8; ++ks) {
            const float4 v0 = *(const float4*)(xr + ks * 32);
            const float4 v1 = *(const float4*)(xr + ks * 32 + 4);
            short8 a;
            a[0] = (short)f2bf(v0.x); a[1] = (short)f2bf(v0.y);
            a[2] = (short)f2bf(v0.z); a[3] = (short)f2bf(v0.w);
            a[4] = (short)f2bf(v1.x); a[5] = (short)f2bf(v1.y);
            a[6] = (short)f2bf(v1.z); a[7] = (short)f2bf(v1.w);
            afrag[ks] = a;
        }
    }

    floatx4 acc[8];
#pragma unroll
    for (int i = 0; i < 8; ++i) acc[i] = floatx4{0.f, 0.f, 0.f, 0.f};

    // ---- 4 chunks of 64 Wt rows (32KB each): stage -> bar -> MFMA -> bar ----
#pragma unroll
    for (int g = 0; g < 4; ++g) {
#pragma unroll
        for (int i = 0; i < 8; ++i) {                 // 32KB, coalesced, swizzled
            const int d = (i << 12) + (tid << 4);
            const short8 v = *(const short8*)((const unsigned char*)Wt + (g << 15) + d);
            *(short8*)(lds + (d ^ (((d >> 9) & 7) << 4))) = v;
        }
        __syncthreads();
#pragma unroll
        for (int e = 0; e < 2; ++e) {
            const int tl = nj + (e << 1);             // local n-tile 0..3
            const int row = (tl << 4) + (lane & 15);
            const int base = row << 9;
            const int swz = (row & 7) << 4;
#pragma unroll
            for (int ks = 0; ks < 8; ++ks) {
                const int cb = (ks << 6) + ((lane >> 4) << 4);
                const short8 b = *(const short8*)(lds + base + (cb ^ swz));
                acc[(g << 1) + e] = __builtin_amdgcn_mfma_f32_16x16x32_bf16(
                    afrag[ks], b, acc[(g << 1) + e], 0, 0, 0);
            }
        }
        __syncthreads();   // computes done before next stage overwrites
    }

    // ---- tanh + partial dot(u) over this wave's 128 cols ----
    // C/D layout: col = lane&15, row = (lane>>4)*4 + j  (verified R1)
    float* part   = (float*)lds;          // [2][32] n-parity partials
    float* ea_lds = (float*)(lds + 256);  // [32]

    float p4[4] = {0.f, 0.f, 0.f, 0.f};
#pragma unroll
    for (int s = 0; s < 8; ++s) {
        const int tg = (s << 1) + nj;                 // global n-tile 0..15
        const int col = (tg << 4) + (lane & 15);
        const float uu = u[col];
        const float bb = bias[col];
#pragma unroll
        for (int j = 0; j < 4; ++j) {
            const float v = acc[s][j] + bb;
            const float e = __expf(2.0f * v);
            const float th = 1.0f - 2.0f * __builtin_amdgcn_rcpf(e + 1.0f);
            p4[j] += th * uu;
        }
    }
#pragma unroll
    for (int j = 0; j < 4; ++j) {
        float sv = p4[j];
        sv += __shfl_xor(sv, 1); sv += __shfl_xor(sv, 2);
        sv += __shfl_xor(sv, 4); sv += __shfl_xor(sv, 8);
        if ((lane & 15) == 0)
            part[(nj << 5) + (mi << 4) + ((lane >> 4) << 2) + j] = sv;
    }
    __syncthreads();
    if (nj == 0 && lane < 16) {           // combine n-halves, exp
        const int r = (mi << 4) + lane;
        const float ea = __expf(part[r] + part[32 + r]);
        ea_lds[r] = ea;
        ea_all[m0 + r] = ea;
    }
    __syncthreads();

    // ---- numerator partial: thread owns col f = tid; x re-read coalesced ----
    {
        float s0 = 0.f;
#pragma unroll
        for (int r = 0; r < 32; ++r)
            s0 = fmaf(x[(size_t)(m0 + r) * 256 + tid], ea_lds[r], s0);
        atomicAdd(&num[(batch << 8) + tid], s0);
    }
}

// denom per batch + finalize
__global__ __launch_bounds__(256) void k_final(const float* __restrict__ ea_all,
                                               const float* __restrict__ num,
                                               float* __restrict__ out) {
    __shared__ float red[8];
    const int b = blockIdx.x, tid = threadIdx.x;
    float s = 0.f;
#pragma unroll
    for (int i = 0; i < 8; ++i) s += ea_all[(b << 11) + (i << 8) + tid];
    s += __shfl_xor(s, 1);  s += __shfl_xor(s, 2);  s += __shfl_xor(s, 4);
    s += __shfl_xor(s, 8);  s += __shfl_xor(s, 16); s += __shfl_xor(s, 32);
    if ((tid & 63) == 0) red[tid >> 6] = s;
    __syncthreads();
    if (tid == 0) red[4] = 1.0f / (red[0] + red[1] + red[2] + red[3] + 1e-7f);
    __syncthreads();
    out[(b << 8) + tid] = num[(b << 8) + tid] * red[4];
}

extern "C" void kernel_launch(void* const* d_in, const int* in_sizes, int n_in,
                              void* d_out, int out_size, void* d_ws, size_t ws_size,
                              hipStream_t stream) {
    const float* x    = (const float*)d_in[0];
    const float* W    = (const float*)d_in[1];
    const float* bias = (const float*)d_in[2];
    const float* u    = (const float*)d_in[3];
    float* out = (float*)d_out;
    unsigned char* ws = (unsigned char*)d_ws;
    unsigned short* Wt = (unsigned short*)(ws);            // 131072 B
    float* ea_all      = (float*)(ws + 131072);            // 524288 B
    float* num         = (float*)(ws + 131072 + 524288);   // 65536 B

    k_wt<<<16, 256, 0, stream>>>(W, Wt, num);
    k_main<<<4096, 256, 0, stream>>>(x, Wt, bias, u, ea_all, num);
    k_final<<<64, 256, 0, stream>>>(ea_all, num, out);
}